// Round 9
// baseline (124.861 us; speedup 1.0000x reference)
//
#include <hip/hip_runtime.h>

#define H 1024
#define W 1024
#define NIMG 8
#define CPT 8                    // columns per thread (2 float4 per tensor)
#define TH 4                     // output rows per wave-tile
#define STRIPS 2                 // y-strips per block (waves 2,3 = strip 1)
#define NBY (H / (TH * STRIPS))  // 128
#define NBLK (NBY * NIMG)        // 1024 blocks = 4/CU = 16 waves/CU
#define NWAVES (NBLK * 4)        // 4096
#define EPS 1e-5f

// Vertical rolling-sum touches. V* are ACCUMULATOR loop-carried state (same
// class as the old wI[] which never spilled) — raw px die immediately.
// No horizontal halo loads at all: each thread only ever loads its own 8 cols.
__device__ __forceinline__ void vadd(const float* __restrict__ Ip,
                                     const float* __restrict__ Jp,
                                     int r, int X,
                                     float vI[8], float vJ[8], float vII[8],
                                     float vJJ[8], float vIJ[8]) {
  const float* Irow = Ip + (size_t)r * W;
  const float* Jrow = Jp + (size_t)r * W;
  float4 i0 = *reinterpret_cast<const float4*>(Irow + X);
  float4 i1 = *reinterpret_cast<const float4*>(Irow + X + 4);
  float4 j0 = *reinterpret_cast<const float4*>(Jrow + X);
  float4 j1 = *reinterpret_cast<const float4*>(Jrow + X + 4);
  const float a[8] = {i0.x,i0.y,i0.z,i0.w,i1.x,i1.y,i1.z,i1.w};
  const float b[8] = {j0.x,j0.y,j0.z,j0.w,j1.x,j1.y,j1.z,j1.w};
  #pragma unroll
  for (int i = 0; i < 8; ++i) {
    vI[i] += a[i]; vJ[i] += b[i];
    vII[i] = fmaf(a[i], a[i], vII[i]);
    vJJ[i] = fmaf(b[i], b[i], vJJ[i]);
    vIJ[i] = fmaf(a[i], b[i], vIJ[i]);
  }
}

__device__ __forceinline__ void vsub(const float* __restrict__ Ip,
                                     const float* __restrict__ Jp,
                                     int r, int X,
                                     float vI[8], float vJ[8], float vII[8],
                                     float vJJ[8], float vIJ[8]) {
  const float* Irow = Ip + (size_t)r * W;
  const float* Jrow = Jp + (size_t)r * W;
  float4 i0 = *reinterpret_cast<const float4*>(Irow + X);
  float4 i1 = *reinterpret_cast<const float4*>(Irow + X + 4);
  float4 j0 = *reinterpret_cast<const float4*>(Jrow + X);
  float4 j1 = *reinterpret_cast<const float4*>(Jrow + X + 4);
  const float a[8] = {i0.x,i0.y,i0.z,i0.w,i1.x,i1.y,i1.z,i1.w};
  const float b[8] = {j0.x,j0.y,j0.z,j0.w,j1.x,j1.y,j1.z,j1.w};
  #pragma unroll
  for (int i = 0; i < 8; ++i) {
    vI[i] -= a[i]; vJ[i] -= b[i];
    vII[i] = fmaf(-a[i], a[i], vII[i]);
    vJJ[i] = fmaf(-b[i], b[i], vJJ[i]);
    vIJ[i] = fmaf(-a[i], b[i], vIJ[i]);
  }
}

// Separable box filter, fully in registers:
//   vertical 9-sums V (rolling, per thread's 8 own cols) updated 2x/row;
//   horizontal 9-sum over V once per OUTPUT row (was: once per touch).
// Wave layout: block = 4 waves = 2 x-halves x 2 y-strips; lane owns 8 cols.
// Horizontal halo: lanes +-1 via __shfl; the single wave boundary (col 512)
// via a 20-float LDS exchange per edge lane per row (1 barrier/row).
// Evidence: r4 L1/3 null, r5 TLP null, r8 load-batch null -> only remaining
// lever is fewer ops+round-trips per output (2.3x fewer loads, 1.5x ops).
__global__ __launch_bounds__(256, 4)
void ncc_main(const float* __restrict__ I, const float* __restrict__ J,
              float* __restrict__ partial) {
  const int tid  = threadIdx.x;
  const int lane = tid & 63, wv = tid >> 6;
  const int xhalf = wv & 1, strip = wv >> 1;
  // XCD-bijective remap (NBLK = 1024 = 8 * 128): XCD k = image k.
  const int bid  = (int)blockIdx.x;
  const int tile = ((bid & 7) << 7) | (bid >> 3);
  const int by   = tile & (NBY - 1);
  const int bz   = tile >> 7;             // image index == XCD id
  const int X  = xhalf * 512 + lane * CPT;
  const int y0 = (by * STRIPS + strip) * TH;
  const size_t img_off = (size_t)bz * H * W;
  const float* Ip = I + img_off;
  const float* Jp = J + img_off;

  __shared__ float xch[STRIPS][2][40];    // [strip][row-parity][L:20 | R:20]

  float vI[8], vJ[8], vII[8], vJJ[8], vIJ[8];
  #pragma unroll
  for (int i = 0; i < 8; ++i) { vI[i]=vJ[i]=vII[i]=vJJ[i]=vIJ[i]=0.f; }
  float acc = 0.f;
  const float inv81 = 1.0f / 81.0f;

  // warm-up: V = sum of rows y0-4 .. y0+4 (OOB rows contribute zero)
  for (int t = 0; t < 9; ++t) {
    const int r = y0 - 4 + t;
    if ((unsigned)r < (unsigned)H) vadd(Ip, Jp, r, X, vI, vJ, vII, vJJ, vIJ);
  }

  for (int k = 0; k < TH; ++k) {
    if (k > 0) {                          // roll window to output row y0+k
      const int re = y0 + 4 + k, rl = y0 - 5 + k;
      if ((unsigned)re < (unsigned)H) vadd(Ip, Jp, re, X, vI, vJ, vII, vJJ, vIJ);
      if ((unsigned)rl < (unsigned)H) vsub(Ip, Jp, rl, X, vI, vJ, vII, vJJ, vIJ);
    }
    const int p = k & 1;
    // boundary lanes publish their V edge (write before barrier)
    if (xhalf == 0) {
      if (lane == 63) {
        #pragma unroll
        for (int j = 0; j < 4; ++j) {
          xch[strip][p][ 0+j] = vI[4+j];  xch[strip][p][ 4+j] = vJ[4+j];
          xch[strip][p][ 8+j] = vII[4+j]; xch[strip][p][12+j] = vJJ[4+j];
          xch[strip][p][16+j] = vIJ[4+j];
        }
      }
    } else {
      if (lane == 0) {
        #pragma unroll
        for (int j = 0; j < 4; ++j) {
          xch[strip][p][20+j] = vI[j];  xch[strip][p][24+j] = vJ[j];
          xch[strip][p][28+j] = vII[j]; xch[strip][p][32+j] = vJJ[j];
          xch[strip][p][36+j] = vIJ[j];
        }
      }
    }
    __syncthreads();

    // left halo: lane-1's V[4..7] (lane 0: LDS across waves, or image zero)
    float hlI[4], hlJ[4], hlII[4], hlJJ[4], hlIJ[4];
    #pragma unroll
    for (int j = 0; j < 4; ++j) {
      hlI[j]  = __shfl_up(vI[4+j], 1, 64);
      hlJ[j]  = __shfl_up(vJ[4+j], 1, 64);
      hlII[j] = __shfl_up(vII[4+j], 1, 64);
      hlJJ[j] = __shfl_up(vJJ[4+j], 1, 64);
      hlIJ[j] = __shfl_up(vIJ[4+j], 1, 64);
    }
    if (lane == 0) {
      #pragma unroll
      for (int j = 0; j < 4; ++j) {
        hlI[j]  = xhalf ? xch[strip][p][ 0+j] : 0.f;
        hlJ[j]  = xhalf ? xch[strip][p][ 4+j] : 0.f;
        hlII[j] = xhalf ? xch[strip][p][ 8+j] : 0.f;
        hlJJ[j] = xhalf ? xch[strip][p][12+j] : 0.f;
        hlIJ[j] = xhalf ? xch[strip][p][16+j] : 0.f;
      }
    }
    // right halo: lane+1's V[0..3] (lane 63: LDS across waves, or image zero)
    float hrI[4], hrJ[4], hrII[4], hrJJ[4], hrIJ[4];
    #pragma unroll
    for (int j = 0; j < 4; ++j) {
      hrI[j]  = __shfl_down(vI[j], 1, 64);
      hrJ[j]  = __shfl_down(vJ[j], 1, 64);
      hrII[j] = __shfl_down(vII[j], 1, 64);
      hrJJ[j] = __shfl_down(vJJ[j], 1, 64);
      hrIJ[j] = __shfl_down(vIJ[j], 1, 64);
    }
    if (lane == 63) {
      #pragma unroll
      for (int j = 0; j < 4; ++j) {
        hrI[j]  = (xhalf == 0) ? xch[strip][p][20+j] : 0.f;
        hrJ[j]  = (xhalf == 0) ? xch[strip][p][24+j] : 0.f;
        hrII[j] = (xhalf == 0) ? xch[strip][p][28+j] : 0.f;
        hrJJ[j] = (xhalf == 0) ? xch[strip][p][32+j] : 0.f;
        hrIJ[j] = (xhalf == 0) ? xch[strip][p][36+j] : 0.f;
      }
    }

    // horizontal rolling 9-sum over [hl0..3, V0..7, hr0..3]; emit 8 outputs
    float sI  = ((hlI[0]+hlI[1])+(hlI[2]+hlI[3])) +
                ((vI[0]+vI[1])+(vI[2]+vI[3])) + vI[4];
    float sJ  = ((hlJ[0]+hlJ[1])+(hlJ[2]+hlJ[3])) +
                ((vJ[0]+vJ[1])+(vJ[2]+vJ[3])) + vJ[4];
    float sII = ((hlII[0]+hlII[1])+(hlII[2]+hlII[3])) +
                ((vII[0]+vII[1])+(vII[2]+vII[3])) + vII[4];
    float sJJ = ((hlJJ[0]+hlJJ[1])+(hlJJ[2]+hlJJ[3])) +
                ((vJJ[0]+vJJ[1])+(vJJ[2]+vJJ[3])) + vJJ[4];
    float sIJ = ((hlIJ[0]+hlIJ[1])+(hlIJ[2]+hlIJ[3])) +
                ((vIJ[0]+vIJ[1])+(vIJ[2]+vIJ[3])) + vIJ[4];
    {
      float cross = fmaf(-(sI * sJ), inv81, sIJ);
      float Iv    = fmaf(-(sI * sI), inv81, sII);
      float Jv    = fmaf(-(sJ * sJ), inv81, sJJ);
      acc = fmaf(cross * cross,
                 __builtin_amdgcn_rcpf(fmaf(Iv, Jv, EPS)), acc);
    }
    #pragma unroll
    for (int i = 1; i < 8; ++i) {
      const float aI  = (i <= 3) ? vI[4+i]  : hrI[i-4];
      const float aJ  = (i <= 3) ? vJ[4+i]  : hrJ[i-4];
      const float aII = (i <= 3) ? vII[4+i] : hrII[i-4];
      const float aJJ = (i <= 3) ? vJJ[4+i] : hrJJ[i-4];
      const float aIJ = (i <= 3) ? vIJ[4+i] : hrIJ[i-4];
      const float dI  = (i <= 4) ? hlI[i-1]  : vI[i-5];
      const float dJ  = (i <= 4) ? hlJ[i-1]  : vJ[i-5];
      const float dII = (i <= 4) ? hlII[i-1] : vII[i-5];
      const float dJJ = (i <= 4) ? hlJJ[i-1] : vJJ[i-5];
      const float dIJ = (i <= 4) ? hlIJ[i-1] : vIJ[i-5];
      sI += aI - dI;  sJ += aJ - dJ;  sII += aII - dII;
      sJJ += aJJ - dJJ;  sIJ += aIJ - dIJ;
      float cross = fmaf(-(sI * sJ), inv81, sIJ);
      float Iv    = fmaf(-(sI * sI), inv81, sII);
      float Jv    = fmaf(-(sJ * sJ), inv81, sJJ);
      acc = fmaf(cross * cross,
                 __builtin_amdgcn_rcpf(fmaf(Iv, Jv, EPS)), acc);
    }
  }

  // wave reduction -> one partial per wave
  #pragma unroll
  for (int off = 32; off > 0; off >>= 1)
    acc += __shfl_down(acc, off, 64);
  if (lane == 0)
    partial[tile * 4 + wv] = acc;
}

__global__ __launch_bounds__(256)
void ncc_reduce(const float* __restrict__ partial, float* __restrict__ out) {
  __shared__ float red[4];
  const int tid = threadIdx.x;
  const float4* p4 = reinterpret_cast<const float4*>(partial);
  float s = 0.f;
  #pragma unroll
  for (int i = tid; i < NWAVES / 4; i += 256) {
    float4 v = p4[i];
    s += (v.x + v.y) + (v.z + v.w);
  }
  #pragma unroll
  for (int off = 32; off > 0; off >>= 1)
    s += __shfl_down(s, off, 64);
  if ((tid & 63) == 0) red[tid >> 6] = s;
  __syncthreads();
  if (tid == 0)
    out[0] = (red[0] + red[1] + red[2] + red[3]) *
             (1.0f / (float)((size_t)NIMG * H * W));
}

extern "C" void kernel_launch(void* const* d_in, const int* in_sizes, int n_in,
                              void* d_out, int out_size, void* d_ws, size_t ws_size,
                              hipStream_t stream) {
  const float* I = (const float*)d_in[0];
  const float* J = (const float*)d_in[1];
  float* out     = (float*)d_out;
  float* partial = (float*)d_ws;            // 4096 * 4 B = 16 KB

  hipLaunchKernelGGL(ncc_main, dim3(NBLK), dim3(256), 0, stream, I, J, partial);
  hipLaunchKernelGGL(ncc_reduce, dim3(1), dim3(256), 0, stream, partial, out);
}

// Round 10
// 121.965 us; speedup vs baseline: 1.0237x; 1.0237x over previous
//
#include <hip/hip_runtime.h>

#define H 1024
#define W 1024
#define NIMG 8
#define CPT 8                   // columns per thread (wave covers 512 cols)
#define TH 4                    // output rows per wave-tile
#define NBX 2                   // x-halves: 64 lanes * 8 cols * 2 = 1024
#define WPB 4                   // waves per block, stacked in y
#define NBY (H / (TH * WPB))    // 64
#define NBLK (NBX * NBY * NIMG) // 1024 blocks = 4/CU = 16 waves/CU
#define NWAVES (NBLK * WPB)     // 4096
#define EPS 1e-5f

// One row-touch for 8 output columns [X, X+8): loads px [X-4, X+12) for both
// tensors (4 edge-guarded float4 each), computes the horizontal 9-box rowsums
// incrementally, and scale-accumulates straight into the window sums.
// No materialized rowsum struct (r7 spill), no loop-carried raw px (r1/r6
// spills), no LDS/barrier (r9 regression). Liveness ~ 32 px + 40 window +
// 5 rowsum + addr ~= 95 regs < 128 cap.
__device__ __forceinline__ void rs_apply(
    const float* __restrict__ Ip, const float* __restrict__ Jp,
    int r, int X, bool okL, bool okR, float scale,
    float wI[CPT], float wJ[CPT], float wII[CPT], float wJJ[CPT],
    float wIJ[CPT])
{
  const float* Irow = Ip + (size_t)r * W;
  const float* Jrow = Jp + (size_t)r * W;
  float a[16], b[16];
  { float4 q0 = *reinterpret_cast<const float4*>(Irow + X);
    float4 q1 = *reinterpret_cast<const float4*>(Irow + X + 4);
    a[4]=q0.x; a[5]=q0.y; a[6]=q0.z; a[7]=q0.w;
    a[8]=q1.x; a[9]=q1.y; a[10]=q1.z; a[11]=q1.w;
    float4 p0 = *reinterpret_cast<const float4*>(Jrow + X);
    float4 p1 = *reinterpret_cast<const float4*>(Jrow + X + 4);
    b[4]=p0.x; b[5]=p0.y; b[6]=p0.z; b[7]=p0.w;
    b[8]=p1.x; b[9]=p1.y; b[10]=p1.z; b[11]=p1.w; }
  if (okL) {
    float4 q = *reinterpret_cast<const float4*>(Irow + X - 4);
    a[0]=q.x; a[1]=q.y; a[2]=q.z; a[3]=q.w;
    float4 p = *reinterpret_cast<const float4*>(Jrow + X - 4);
    b[0]=p.x; b[1]=p.y; b[2]=p.z; b[3]=p.w;
  } else { a[0]=a[1]=a[2]=a[3]=0.f; b[0]=b[1]=b[2]=b[3]=0.f; }
  if (okR) {
    float4 q = *reinterpret_cast<const float4*>(Irow + X + 8);
    a[12]=q.x; a[13]=q.y; a[14]=q.z; a[15]=q.w;
    float4 p = *reinterpret_cast<const float4*>(Jrow + X + 8);
    b[12]=p.x; b[13]=p.y; b[14]=p.z; b[15]=p.w;
  } else { a[12]=a[13]=a[14]=a[15]=0.f; b[12]=b[13]=b[14]=b[15]=0.f; }

  float sI=0.f, sJ=0.f, sII=0.f, sJJ=0.f, sIJ=0.f;
  #pragma unroll
  for (int k = 0; k < 9; ++k) {
    sI += a[k]; sJ += b[k];
    sII = fmaf(a[k], a[k], sII);
    sJJ = fmaf(b[k], b[k], sJJ);
    sIJ = fmaf(a[k], b[k], sIJ);
  }
  wI[0]  = fmaf(scale, sI,  wI[0]);
  wJ[0]  = fmaf(scale, sJ,  wJ[0]);
  wII[0] = fmaf(scale, sII, wII[0]);
  wJJ[0] = fmaf(scale, sJJ, wJJ[0]);
  wIJ[0] = fmaf(scale, sIJ, wIJ[0]);
  #pragma unroll
  for (int i = 1; i < CPT; ++i) {
    float an=a[i+8], al=a[i-1], bn=b[i+8], bl=b[i-1];
    sI += an - al;  sJ += bn - bl;
    sII = fmaf(-al, al, fmaf(an, an, sII));
    sJJ = fmaf(-bl, bl, fmaf(bn, bn, sJJ));
    sIJ = fmaf(-al, bl, fmaf(an, bn, sIJ));
    wI[i]  = fmaf(scale, sI,  wI[i]);
    wJ[i]  = fmaf(scale, sJ,  wJ[i]);
    wII[i] = fmaf(scale, sII, wII[i]);
    wJJ[i] = fmaf(scale, sJJ, wJJ[i]);
    wIJ[i] = fmaf(scale, sIJ, wIJ[i]);
  }
}

// No LDS, no barriers. Each wave walks a 512-col x 4-row tile; per-thread
// 8-col strip with vertical running window sums in registers.
// CPT=8/TH=4 minimizes float4-loads per output (3.75 vs r2's 4.31) under the
// >=16 waves/CU constraint, and amortizes the 9-wide horizontal sum over 8
// cols (-12% VALU/output). Same no-sync structure as the 110 us r2 kernel.
// Evidence: TLP x2 null (r5); L1-traffic/3 null (r4: DS cost == L1 savings);
// load batching null (r8); cross-iter pipelines spill (r1/r6/r7); barriered
// separability regresses (r9). Inputs are L3-resident across iterations
// (r9: steady dispatch with ~0 hbm_bytes) -> kernel is L1/L2/L3-path bound.
__global__ __launch_bounds__(256, 4)
void ncc_main(const float* __restrict__ I, const float* __restrict__ J,
              float* __restrict__ partial) {
  const int tid  = threadIdx.x;
  const int lane = tid & 63, wv = tid >> 6;
  // XCD-bijective remap (NBLK = 1024 = 8 * 128): XCD k (= bid % 8) processes
  // exactly image k -> halo re-reads stay in one XCD's L2/L3 slice.
  const int bid  = (int)blockIdx.x;
  const int tile = ((bid & 7) << 7) | (bid >> 3);
  const int bx   = tile & (NBX - 1);
  const int rest = tile >> 1;             // [0, 512)
  const int by   = rest & (NBY - 1);
  const int bz   = rest >> 6;             // image index == XCD id
  const int X  = bx * 512 + lane * CPT;
  const int y0 = (by * WPB + wv) * TH;
  const bool okL = (X >= 4);                    // false only bx=0,lane=0
  const bool okR = (X + 12 <= W);               // false only bx=1,lane=63
  const size_t img_off = (size_t)bz * H * W;
  const float* Ip = I + img_off;
  const float* Jp = J + img_off;

  float wI[CPT], wJ[CPT], wII[CPT], wJJ[CPT], wIJ[CPT];
  #pragma unroll
  for (int i = 0; i < CPT; ++i) { wI[i]=wJ[i]=wII[i]=wJJ[i]=wIJ[i]=0.f; }
  float acc = 0.f;
  const float inv81 = 1.0f / 81.0f;

  auto apply = [&](int r, float sgn) {
    if ((unsigned)r < (unsigned)H)        // wave-uniform row guard
      rs_apply(Ip, Jp, r, X, okL, okR, sgn, wI, wJ, wII, wJJ, wIJ);
  };
  auto emit = [&]() {
    #pragma unroll
    for (int i = 0; i < CPT; ++i) {
      float cross = fmaf(-(wI[i] * wJ[i]), inv81, wIJ[i]);
      float Iv    = fmaf(-(wI[i] * wI[i]), inv81, wII[i]);
      float Jv    = fmaf(-(wJ[i] * wJ[i]), inv81, wJJ[i]);
      acc = fmaf(cross * cross,
                 __builtin_amdgcn_rcpf(fmaf(Iv, Jv, EPS)), acc);
    }
  };

  // warm-up: rows y0-4 .. y0+3
  for (int k = 0; k < 8; ++k) apply(y0 - 4 + k, 1.0f);
  // first output row: add y0+4, window = rows y0-4..y0+4
  apply(y0 + 4, 1.0f);
  emit();
  // steady state: add r, drop r-9, emit y=r-4
  for (int k = 0; k < TH - 1; ++k) {
    apply(y0 + 5 + k, 1.0f);
    apply(y0 - 4 + k, -1.0f);
    emit();
  }

  // wave reduction -> one partial per wave (no LDS, no barrier)
  #pragma unroll
  for (int off = 32; off > 0; off >>= 1)
    acc += __shfl_down(acc, off, 64);
  if (lane == 0)
    partial[tile * WPB + wv] = acc;
}

__global__ __launch_bounds__(256)
void ncc_reduce(const float* __restrict__ partial, float* __restrict__ out) {
  __shared__ float red[4];
  const int tid = threadIdx.x;
  const float4* p4 = reinterpret_cast<const float4*>(partial);
  float s = 0.f;
  #pragma unroll
  for (int i = tid; i < NWAVES / 4; i += 256) {
    float4 v = p4[i];
    s += (v.x + v.y) + (v.z + v.w);
  }
  #pragma unroll
  for (int off = 32; off > 0; off >>= 1)
    s += __shfl_down(s, off, 64);
  if ((tid & 63) == 0) red[tid >> 6] = s;
  __syncthreads();
  if (tid == 0)
    out[0] = (red[0] + red[1] + red[2] + red[3]) *
             (1.0f / (float)((size_t)NIMG * H * W));
}

extern "C" void kernel_launch(void* const* d_in, const int* in_sizes, int n_in,
                              void* d_out, int out_size, void* d_ws, size_t ws_size,
                              hipStream_t stream) {
  const float* I = (const float*)d_in[0];
  const float* J = (const float*)d_in[1];
  float* out     = (float*)d_out;
  float* partial = (float*)d_ws;            // 4096 * 4 B = 16 KB

  hipLaunchKernelGGL(ncc_main, dim3(NBLK), dim3(256), 0, stream, I, J, partial);
  hipLaunchKernelGGL(ncc_reduce, dim3(1), dim3(256), 0, stream, partial, out);
}